// Round 1
// baseline (669.841 us; speedup 1.0000x reference)
//
#include <hip/hip_runtime.h>

typedef _Float16 f16;
typedef __attribute__((ext_vector_type(8))) _Float16 f16x8;
typedef __attribute__((ext_vector_type(4))) _Float16 f16x4;
typedef __attribute__((ext_vector_type(4))) float f32x4;

// ws layout (f16 elements)
#define WS_W1T 0                       // [512][128]
#define WS_W2T 65536                   // [512][512]
#define WS_W3T (65536 + 262144)        // [256][512], rows 251..255 zero

// ---------------------------------------------------------------------------
// Prologue: convert + transpose weights to f16, K-contiguous rows (W^T[n][k])
// ---------------------------------------------------------------------------
__global__ __launch_bounds__(256) void convert_weights_k(
    const float* __restrict__ W1, const float* __restrict__ W2,
    const float* __restrict__ W3, f16* __restrict__ ws)
{
  int idx = blockIdx.x * 256 + threadIdx.x;
  if (idx < 65536) {                       // W1T[n][k] = W1[k][n], n<512,k<128
    int n = idx >> 7, k = idx & 127;
    ws[WS_W1T + idx] = (f16)W1[k * 512 + n];
  } else if (idx < 327680) {               // W2T[n][k] = W2[k][n], 512x512
    int i = idx - 65536;
    int n = i >> 9, k = i & 511;
    ws[WS_W2T + i] = (f16)W2[k * 512 + n];
  } else if (idx < 458752) {               // W3T[n][k] = W3[k][n], n<251 else 0
    int i = idx - 327680;
    int n = i >> 9, k = i & 511;
    ws[WS_W3T + i] = (n < 251) ? (f16)W3[k * 251 + n] : (f16)(0.0f);
  }
}

// Swizzled LDS vector read: 16B at row m, byte offset kb (16B aligned)
__device__ __forceinline__ f16x8 lds_ld8(const char* base, int m, int strideB, int kb) {
  return *(const f16x8*)(base + m * strideB + (kb ^ ((m & 7) << 4)));
}

// ---------------------------------------------------------------------------
// Fused: x->MLP(f16 MFMA)->softmax->C51 projection.  BM=64 rows, 8 waves.
// ---------------------------------------------------------------------------
__global__ __launch_bounds__(512, 2) void fused_c51_k(
    const float* __restrict__ obs, const float* __restrict__ act,
    const float* __restrict__ rewards, const float* __restrict__ bootstrap,
    const float* __restrict__ discount, const float* __restrict__ q_support,
    const float* __restrict__ bias1, const float* __restrict__ bias2,
    const float* __restrict__ bias3, const f16* __restrict__ ws,
    float* __restrict__ out)
{
  extern __shared__ char smem[];
  char* xs = smem;                     // [64][128] f16 swizzled (16 KB)
  char* h1 = smem + 16384;             // [64][512] f16 swizzled (64 KB)
  char* h2 = smem + 81920;             // [64][512] f16 swizzled (64 KB)
  char* lg = smem;                     // [64][256] f32 swizzled (overlays xs+h1)
  float* pr = (float*)(smem + 81920);  // [64][256] f32 (overlays h2)

  const f16* W1T = ws + WS_W1T;
  const f16* W2T = ws + WS_W2T;
  const f16* W3T = ws + WS_W3T;

  const int tid = threadIdx.x;
  const int lane = tid & 63;
  const int w = tid >> 6;          // wave id 0..7
  const int l15 = lane & 15;
  const int lh = lane >> 4;        // 0..3
  const long rowBase = (long)blockIdx.x * 64;

  // ---- Phase A: stage x = concat(obs, act) as f16 into LDS (granule = 8 f16)
  #pragma unroll
  for (int i = 0; i < 2; ++i) {
    int chunk = tid + i * 512;         // 0..1023
    int m = chunk >> 4, g = chunk & 15;
    long row = rowBase + m;
    const float* src = (g < 12) ? (obs + row * 96 + g * 8)
                                : (act + row * 32 + (g - 12) * 8);
    float4 lo = ((const float4*)src)[0];
    float4 hi = ((const float4*)src)[1];
    f16x8 v;
    v[0] = (f16)lo.x; v[1] = (f16)lo.y; v[2] = (f16)lo.z; v[3] = (f16)lo.w;
    v[4] = (f16)hi.x; v[5] = (f16)hi.y; v[6] = (f16)hi.z; v[7] = (f16)hi.w;
    *(f16x8*)(xs + m * 256 + ((g * 16) ^ ((m & 7) << 4))) = v;
  }
  __syncthreads();

  // ---- Stage 1: h1 = leaky(x @ W1 + b1), K=128. Wave n-slice: 64 cols.
  {
    #pragma unroll
    for (int nt = 0; nt < 4; ++nt) {
      const int nBase = w * 64 + nt * 16;
      const f16* wp = W1T + (nBase + l15) * 128 + lh * 8;
      f16x8 a[4];
      #pragma unroll
      for (int ks = 0; ks < 4; ++ks) a[ks] = *(const f16x8*)(wp + ks * 32);
      f32x4 bias = *(const f32x4*)(bias1 + nBase + lh * 4);
      #pragma unroll
      for (int mtp = 0; mtp < 4; mtp += 2) {
        f32x4 acc0 = {0.f, 0.f, 0.f, 0.f}, acc1 = {0.f, 0.f, 0.f, 0.f};
        #pragma unroll
        for (int ks = 0; ks < 4; ++ks) {
          int kb = ks * 64 + lh * 16;
          f16x8 bf0 = lds_ld8(xs, mtp * 16 + l15, 256, kb);
          f16x8 bf1 = lds_ld8(xs, mtp * 16 + 16 + l15, 256, kb);
          acc0 = __builtin_amdgcn_mfma_f32_16x16x32_f16(a[ks], bf0, acc0, 0, 0, 0);
          acc1 = __builtin_amdgcn_mfma_f32_16x16x32_f16(a[ks], bf1, acc1, 0, 0, 0);
        }
        #pragma unroll
        for (int half = 0; half < 2; ++half) {
          f32x4 acc = half ? acc1 : acc0;
          int m = (mtp + half) * 16 + l15;
          f16x4 hv;
          #pragma unroll
          for (int r = 0; r < 4; ++r) {
            float v = acc[r] + bias[r];
            hv[r] = (f16)(v > 0.f ? v : 0.01f * v);
          }
          *(f16x4*)(h1 + m * 1024 + (((nBase + lh * 4) * 2) ^ ((m & 7) << 4))) = hv;
        }
      }
    }
  }
  __syncthreads();

  // ---- Stage 2: h2 = leaky(h1 @ W2 + b2), K=512.
  {
    #pragma unroll
    for (int nt = 0; nt < 4; ++nt) {
      const int nBase = w * 64 + nt * 16;
      const f16* wp = W2T + (nBase + l15) * 512 + lh * 8;
      f16x8 a[16];
      #pragma unroll
      for (int ks = 0; ks < 16; ++ks) a[ks] = *(const f16x8*)(wp + ks * 32);
      f32x4 bias = *(const f32x4*)(bias2 + nBase + lh * 4);
      #pragma unroll
      for (int mtp = 0; mtp < 4; mtp += 2) {
        f32x4 acc0 = {0.f, 0.f, 0.f, 0.f}, acc1 = {0.f, 0.f, 0.f, 0.f};
        #pragma unroll
        for (int ks = 0; ks < 16; ++ks) {
          int kb = ks * 64 + lh * 16;
          f16x8 bf0 = lds_ld8(h1, mtp * 16 + l15, 1024, kb);
          f16x8 bf1 = lds_ld8(h1, mtp * 16 + 16 + l15, 1024, kb);
          acc0 = __builtin_amdgcn_mfma_f32_16x16x32_f16(a[ks], bf0, acc0, 0, 0, 0);
          acc1 = __builtin_amdgcn_mfma_f32_16x16x32_f16(a[ks], bf1, acc1, 0, 0, 0);
        }
        #pragma unroll
        for (int half = 0; half < 2; ++half) {
          f32x4 acc = half ? acc1 : acc0;
          int m = (mtp + half) * 16 + l15;
          f16x4 hv;
          #pragma unroll
          for (int r = 0; r < 4; ++r) {
            float v = acc[r] + bias[r];
            hv[r] = (f16)(v > 0.f ? v : 0.01f * v);
          }
          *(f16x4*)(h2 + m * 1024 + (((nBase + lh * 4) * 2) ^ ((m & 7) << 4))) = hv;
        }
      }
    }
  }
  __syncthreads();

  // ---- Stage 3: logits = h2 @ W3 (b3 added in epilogue), K=512, N=256.
  {
    #pragma unroll
    for (int nt = 0; nt < 2; ++nt) {
      const int nBase = w * 32 + nt * 16;
      const f16* wp = W3T + (nBase + l15) * 512 + lh * 8;
      f16x8 a[16];
      #pragma unroll
      for (int ks = 0; ks < 16; ++ks) a[ks] = *(const f16x8*)(wp + ks * 32);
      #pragma unroll
      for (int mtp = 0; mtp < 4; mtp += 2) {
        f32x4 acc0 = {0.f, 0.f, 0.f, 0.f}, acc1 = {0.f, 0.f, 0.f, 0.f};
        #pragma unroll
        for (int ks = 0; ks < 16; ++ks) {
          int kb = ks * 64 + lh * 16;
          f16x8 bf0 = lds_ld8(h2, mtp * 16 + l15, 1024, kb);
          f16x8 bf1 = lds_ld8(h2, mtp * 16 + 16 + l15, 1024, kb);
          acc0 = __builtin_amdgcn_mfma_f32_16x16x32_f16(a[ks], bf0, acc0, 0, 0, 0);
          acc1 = __builtin_amdgcn_mfma_f32_16x16x32_f16(a[ks], bf1, acc1, 0, 0, 0);
        }
        #pragma unroll
        for (int half = 0; half < 2; ++half) {
          f32x4 acc = half ? acc1 : acc0;
          int m = (mtp + half) * 16 + l15;
          *(f32x4*)(lg + m * 1024 + (((nBase + lh * 4) * 4) ^ ((m & 7) << 4))) = acc;
        }
      }
    }
  }
  __syncthreads();

  // ---- Phase E: softmax + C51 projection. Wave w owns rows w*8 .. w*8+7.
  {
    float zc[4], b3c[4];
    #pragma unroll
    for (int j = 0; j < 4; ++j) {
      int c = lane + j * 64;
      bool ok = c < 251;
      zc[j]  = ok ? q_support[c] : 0.f;
      b3c[j] = ok ? bias3[c] : 0.f;
    }
    for (int i = 0; i < 8; ++i) {
      const int m = w * 8 + i;
      const long row = rowBase + m;
      // zero this row's projection bins (row touched only by this wave)
      #pragma unroll
      for (int j = 0; j < 4; ++j) pr[m * 256 + j * 64 + lane] = 0.f;
      // gather logits + bias
      float v[4];
      #pragma unroll
      for (int j = 0; j < 4; ++j) {
        int c = lane + j * 64;
        float t = *(const float*)(lg + m * 1024 + ((c * 4) ^ ((m & 7) << 4)));
        v[j] = (c < 251) ? t + b3c[j] : -3.0e38f;
      }
      float mx = fmaxf(fmaxf(v[0], v[1]), fmaxf(v[2], v[3]));
      #pragma unroll
      for (int s = 1; s < 64; s <<= 1) mx = fmaxf(mx, __shfl_xor(mx, s, 64));
      float e[4];
      float sum = 0.f;
      #pragma unroll
      for (int j = 0; j < 4; ++j) {
        int c = lane + j * 64;
        e[j] = (c < 251) ? __expf(v[j] - mx) : 0.f;
        sum += e[j];
      }
      #pragma unroll
      for (int s = 1; s < 64; s <<= 1) sum += __shfl_xor(sum, s, 64);
      float inv = 1.f / sum;
      float rw = rewards[row];
      float bd = __fmul_rn(bootstrap[row], discount[row]);
      #pragma unroll
      for (int j = 0; j < 4; ++j) {
        int c = lane + j * 64;
        if (c < 251) {
          float p = e[j] * inv;
          // exact replication of reference fp ops (no FMA contraction)
          float tz = __fadd_rn(rw, __fmul_rn(bd, zc[j]));
          tz = fminf(fmaxf(tz, -100.f), 100.f);
          float b = __fdiv_rn(__fadd_rn(tz, 100.f), 0.8f);
          float lf = floorf(b), uf = ceilf(b);
          int li = (int)lf, ui = (int)uf;
          bool eq = (li == ui);
          int li2 = li - ((eq && (ui > 0)) ? 1 : 0);
          int ui2 = ui + ((eq && (li < 250)) ? 1 : 0);
          atomicAdd(&pr[m * 256 + li2], p * ((float)ui2 - b));
          atomicAdd(&pr[m * 256 + ui2], p * (b - (float)li2));
        }
      }
      // write out (atomics from this wave complete in LDS program order)
      #pragma unroll
      for (int j = 0; j < 4; ++j) {
        int c = lane + j * 64;
        if (c < 251) out[row * 251 + c] = pr[m * 256 + c];
      }
    }
  }
}

extern "C" void kernel_launch(void* const* d_in, const int* in_sizes, int n_in,
                              void* d_out, int out_size, void* d_ws, size_t ws_size,
                              hipStream_t stream) {
  (void)n_in; (void)out_size; (void)ws_size;
  const float* obs       = (const float*)d_in[0];
  const float* actions   = (const float*)d_in[1];
  const float* rewards   = (const float*)d_in[2];
  const float* bootstrap = (const float*)d_in[3];
  const float* discount  = (const float*)d_in[4];
  const float* q_support = (const float*)d_in[5];
  const float* W1 = (const float*)d_in[6];
  const float* b1 = (const float*)d_in[7];
  const float* W2 = (const float*)d_in[8];
  const float* b2 = (const float*)d_in[9];
  const float* W3 = (const float*)d_in[10];
  const float* b3 = (const float*)d_in[11];
  float* out = (float*)d_out;
  f16* ws = (f16*)d_ws;
  const int B = in_sizes[2];

  hipLaunchKernelGGL(convert_weights_k, dim3(1792), dim3(256), 0, stream,
                     W1, W2, W3, ws);

  const int LDS_BYTES = 147456;  // 144 KB
  hipFuncSetAttribute(reinterpret_cast<const void*>(fused_c51_k),
                      hipFuncAttributeMaxDynamicSharedMemorySize, LDS_BYTES);
  hipLaunchKernelGGL(fused_c51_k, dim3(B / 64), dim3(512), LDS_BYTES, stream,
                     obs, actions, rewards, bootstrap, discount, q_support,
                     b1, b2, b3, ws, out);
}